// Round 8
// baseline (756.447 us; speedup 1.0000x reference)
//
#include <hip/hip_runtime.h>
#include <hip/hip_bf16.h>

typedef unsigned short u16;

#define NN    100000     // total nodes
#define NU    50000      // users
#define DD    64         // latdim
#define HHY   128        // hyperNum
#define EE    1600000    // nnz
#define NCHK  384        // split-K chunks for lat (part = 12.58 MB, fits slab2 upper half)
#define CROWS 261        // ceil(NN/NCHK)
#define NSB   391        // ceil(NN/256) scan blocks
#define SCB   6250       // scatter / gate / prep chunk count (EE/256)
#define LPB   768        // latpart flat blocks (NCHK chunks x 2 h-halves)
#define BUCKW 400000     // CSR bucket width in entries (EE/4) = 3.2 MB, fits per-XCD L2
#define CPAD  16         // histogram padding: 1 counter per 64B line (kills line contention)

__device__ __forceinline__ float us2f(u16 u) {
    union { unsigned int i; float f; } v; v.i = ((unsigned int)u) << 16; return v.f;
}
__device__ __forceinline__ u16 f2us(float f) {
    __hip_bfloat16 b = __float2bfloat16(f);
    return *reinterpret_cast<u16*>(&b);
}
__device__ __forceinline__ float lrelu(float x) { return x > 0.f ? x : 0.5f * x; }

// ================= device bodies (shared by fused wrappers) =================

// allhyper for 8 rows, reading fp32 embeds directly (no dependence on cur)
__device__ __forceinline__ void allhyper_body(int ab,
        const float4* __restrict__ u, const float4* __restrict__ it,
        const float* __restrict__ Hyper, u16* __restrict__ hyp) {
    int t = threadIdx.x;
    int hg = t & 31;                      // 32 groups of 4 h
    int n = ab * 8 + (t >> 5);
    const float4* src = (n < NU) ? (u + (size_t)n * 16) : (it + (size_t)(n - NU) * 16);
    float4 er[16];
#pragma unroll
    for (int i = 0; i < 16; i++) er[i] = src[i];
    float a0 = 0.f, a1 = 0.f, a2 = 0.f, a3 = 0.f;
#pragma unroll
    for (int i = 0; i < 16; i++) {
        float ev[4] = { er[i].x, er[i].y, er[i].z, er[i].w };
#pragma unroll
        for (int k = 0; k < 4; k++) {
            int d = i * 4 + k;
            float e = ev[k];
            float4 hq = *(const float4*)(Hyper + (size_t)d * HHY + hg * 4);
            a0 += e * hq.x; a1 += e * hq.y;
            a2 += e * hq.z; a3 += e * hq.w;
        }
    }
    u16* o = hyp + (size_t)n * HHY + hg * 4;
    o[0] = f2us(a0); o[1] = f2us(a1); o[2] = f2us(a2); o[3] = f2us(a3);
}

__device__ __forceinline__ void latpart_body(int chunk, int yy,
        const u16* __restrict__ cur, const u16* __restrict__ hyp,
        float* __restrict__ part) {
    int t = threadIdx.x;
    int w = t >> 6, d = t & 63;
    int h0 = (yy * 4 + w) * 16;
    int c0 = chunk * CROWS;
    int c1 = c0 + CROWS; if (c1 > NN) c1 = NN;
    float acc[16];
#pragma unroll
    for (int j = 0; j < 16; j++) acc[j] = 0.f;
    for (int n = c0; n < c1; n++) {
        float cv = us2f(cur[(size_t)n * DD + d]);
        const ushort4* hp = (const ushort4*)(hyp + (size_t)n * HHY + h0);
        u16 ha[16];
        *(ushort4*)(ha + 0)  = hp[0];
        *(ushort4*)(ha + 4)  = hp[1];
        *(ushort4*)(ha + 8)  = hp[2];
        *(ushort4*)(ha + 12) = hp[3];
#pragma unroll
        for (int j = 0; j < 16; j++) acc[j] += us2f(ha[j]) * cv;
    }
#pragma unroll
    for (int j = 0; j < 16; j++)
        part[((size_t)chunk * HHY + h0 + j) * DD + d] = acc[j];
}

__device__ __forceinline__ void gate_body(int ch,
        const ushort4* __restrict__ cur, const float4* __restrict__ z,
        ushort4* __restrict__ gate) {
    int idx = ch * 256 + threadIdx.x;      // ch < SCB -> idx < NN*DD/4
    ushort4 c = cur[idx];
    float4 zz = z[idx];
    ushort4 o;
    o.x = f2us(us2f(c.x) * (2.f / (1.f + __expf(-zz.x)) - 1.f));
    o.y = f2us(us2f(c.y) * (2.f / (1.f + __expf(-zz.y)) - 1.f));
    o.z = f2us(us2f(c.z) * (2.f / (1.f + __expf(-zz.z)) - 1.f));
    o.w = f2us(us2f(c.w) * (2.f / (1.f + __expf(-zz.w)) - 1.f));
    gate[idx] = o;
}

// bucketed scatter: block handles (chunk, bucket); writes only edges whose CSR
// position falls in its bucket's 3.2 MB window (XCD-local L2 merging).
__device__ __forceinline__ void scatter_body(int chunk, int bucket,
        const int* __restrict__ pos,
        const int* __restrict__ cols, const float* __restrict__ vals,
        int2* __restrict__ csr) {
    int e = chunk * 256 + threadIdx.x;     // < EE
    int p = pos[e];
    if ((unsigned)p / (unsigned)BUCKW == (unsigned)bucket) {
        csr[p] = make_int2(cols[e], __float_as_int(vals[e]));
    }
}

__device__ __forceinline__ void spmm_body(int b,
        const int* __restrict__ row_start, const int2* __restrict__ csr,
        const u16* __restrict__ gate, float* __restrict__ out0) {
    int w = threadIdx.x >> 6, d = threadIdx.x & 63;
    int row = b * 4 + w;                   // b < NN/4 -> row < NN
    int s = row_start[row], e = row_start[row + 1];
    float a0 = 0.f, a1 = 0.f, a2 = 0.f, a3 = 0.f;
    float a4 = 0.f, a5 = 0.f, a6 = 0.f, a7 = 0.f;
    int j = s;
    for (; j + 8 <= e; j += 8) {
        int2 c0 = csr[j],     c1 = csr[j + 1], c2 = csr[j + 2], c3 = csr[j + 3];
        int2 c4 = csr[j + 4], c5 = csr[j + 5], c6 = csr[j + 6], c7 = csr[j + 7];
        float g0 = us2f(gate[(size_t)c0.x * DD + d]);
        float g1 = us2f(gate[(size_t)c1.x * DD + d]);
        float g2 = us2f(gate[(size_t)c2.x * DD + d]);
        float g3 = us2f(gate[(size_t)c3.x * DD + d]);
        float g4 = us2f(gate[(size_t)c4.x * DD + d]);
        float g5 = us2f(gate[(size_t)c5.x * DD + d]);
        float g6 = us2f(gate[(size_t)c6.x * DD + d]);
        float g7 = us2f(gate[(size_t)c7.x * DD + d]);
        a0 += __int_as_float(c0.y) * g0;
        a1 += __int_as_float(c1.y) * g1;
        a2 += __int_as_float(c2.y) * g2;
        a3 += __int_as_float(c3.y) * g3;
        a4 += __int_as_float(c4.y) * g4;
        a5 += __int_as_float(c5.y) * g5;
        a6 += __int_as_float(c6.y) * g6;
        a7 += __int_as_float(c7.y) * g7;
    }
    for (; j + 4 <= e; j += 4) {
        int2 c0 = csr[j], c1 = csr[j + 1], c2 = csr[j + 2], c3 = csr[j + 3];
        float g0 = us2f(gate[(size_t)c0.x * DD + d]);
        float g1 = us2f(gate[(size_t)c1.x * DD + d]);
        float g2 = us2f(gate[(size_t)c2.x * DD + d]);
        float g3 = us2f(gate[(size_t)c3.x * DD + d]);
        a0 += __int_as_float(c0.y) * g0;
        a1 += __int_as_float(c1.y) * g1;
        a2 += __int_as_float(c2.y) * g2;
        a3 += __int_as_float(c3.y) * g3;
    }
    for (; j < e; j++) {
        int2 cv = csr[j];
        a0 += __int_as_float(cv.y) * us2f(gate[(size_t)cv.x * DD + d]);
    }
    float acc = ((a0 + a1) + (a2 + a3)) + ((a4 + a5) + (a6 + a7));
    out0[(size_t)row * DD + d] = lrelu(acc);
}

__device__ __forceinline__ void latreduce_body(int lb,
        const float* __restrict__ part, float* __restrict__ lat) {
    int idx = lb * 256 + threadIdx.x;      // h*64+d, 8192 total
    float s0 = 0.f, s1 = 0.f, s2 = 0.f, s3 = 0.f;
    for (int c = 0; c < NCHK; c += 4) {
        s0 += part[(size_t)(c + 0) * HHY * DD + idx];
        s1 += part[(size_t)(c + 1) * HHY * DD + idx];
        s2 += part[(size_t)(c + 2) * HHY * DD + idx];
        s3 += part[(size_t)(c + 3) * HHY * DD + idx];
    }
    lat[idx] = lrelu((s0 + s1) + (s2 + s3));
}

// ================= kernels =================

// fused: histprep (prep embeds0->bf16 cur, padded hist counts+ranks) || allhyper
__global__ __launch_bounds__(256) void k_hp_ah(const int* __restrict__ rows,
                                               int* __restrict__ cnt,
                                               int* __restrict__ ranks,
                                               const float4* __restrict__ u,
                                               const float4* __restrict__ it,
                                               ushort4* __restrict__ cur,
                                               const float* __restrict__ Hyper,
                                               u16* __restrict__ hyp) {
    int bid = blockIdx.x;
    int p = bid % 3, q = bid / 3;          // grid = 3*SCB: 1 prep/hist : 2 allhyper
    if (p == 0) {
        int e = q * 256 + threadIdx.x;     // < EE
        const int HALF = NU * DD / 4;      // 800000
        float4 f = (e < HALF) ? u[e] : it[e - HALF];
        ushort4 o; o.x = f2us(f.x); o.y = f2us(f.y); o.z = f2us(f.z); o.w = f2us(f.w);
        cur[e] = o;
        // padded: one counter per 64B line -> contention/line = true row degree only
        ranks[e] = atomicAdd(&cnt[(size_t)rows[e] * CPAD], 1);
    } else {
        allhyper_body(q * 2 + (p - 1), u, it, Hyper, hyp);   // exact coverage
    }
}

// phase 1: per-block sums of padded cnt (256 counters per block)
__global__ __launch_bounds__(256) void k_blocksum(const int* __restrict__ cnt,
                                                  int* __restrict__ bsum) {
    __shared__ int s[256];
    int t = threadIdx.x;
    int i = blockIdx.x * 256 + t;
    s[t] = (i < NN) ? cnt[(size_t)i * CPAD] : 0;
    __syncthreads();
    for (int off = 128; off > 0; off >>= 1) {
        if (t < off) s[t] += s[t + off];
        __syncthreads();
    }
    if (t == 0) bsum[blockIdx.x] = s[0];
}

// phase 2: exclusive scan of the 391 block sums (single small block)
__global__ __launch_bounds__(512) void k_scanb(int* __restrict__ bsum) {
    __shared__ int s[512];
    int t = threadIdx.x;
    int v = (t < NSB) ? bsum[t] : 0;
    s[t] = v;
    __syncthreads();
    for (int off = 1; off < 512; off <<= 1) {
        int add = (t >= off) ? s[t - off] : 0;
        __syncthreads();
        s[t] += add;
        __syncthreads();
    }
    if (t < NSB) bsum[t] = s[t] - v;   // exclusive
}

// phase 3: block-local scan + block offset -> row_start
__global__ __launch_bounds__(256) void k_scanfinal(const int* __restrict__ cnt,
                                                   const int* __restrict__ bsum,
                                                   int* __restrict__ row_start) {
    __shared__ int s[256];
    int t = threadIdx.x;
    int i = blockIdx.x * 256 + t;
    int v = (i < NN) ? cnt[(size_t)i * CPAD] : 0;
    s[t] = v;
    __syncthreads();
    for (int off = 1; off < 256; off <<= 1) {
        int add = (t >= off) ? s[t - off] : 0;
        __syncthreads();
        s[t] += add;
        __syncthreads();
    }
    int excl = s[t] - v + bsum[blockIdx.x];
    if (i < NN) row_start[i] = excl;
    if (i == NN - 1) row_start[NN] = excl + v;   // total nnz
}

// pos[e] = final CSR position of edge e (coalesced; row_start gather is L2-resident)
__global__ __launch_bounds__(256) void k_pos(const int* __restrict__ rows,
                                             const int* __restrict__ ranks,
                                             const int* __restrict__ row_start,
                                             int* __restrict__ pos) {
    int e = blockIdx.x * 256 + threadIdx.x;   // grid = SCB -> e < EE
    pos[e] = row_start[rows[e]] + ranks[e];
}

// fused layer-0: latpart0 (first 768 long blocks) || XCD-bucketed scatter.
__global__ __launch_bounds__(256) void k_fused0(const int* __restrict__ pos,
                                                const int* __restrict__ cols,
                                                const float* __restrict__ vals,
                                                int2* __restrict__ csr,
                                                const u16* __restrict__ cur,
                                                const u16* __restrict__ hyp,
                                                float* __restrict__ part) {
    int bid = blockIdx.x;
    if (bid < LPB) {
        latpart_body(bid >> 1, bid & 1, cur, hyp, part);
    } else {
        int sid = bid - LPB;               // LPB%8==0 so sid%8 == bid%8 == XCD
        int xcd = sid & 7;
        int bucket = xcd & 3;
        int chunk = (sid >> 3) * 2 + (xcd >> 2);   // 0..6249
        scatter_body(chunk, bucket, pos, cols, vals, csr);
    }
}

// standalone gate (layer 0 only; layer 1's gate is fused with latpart1)
__global__ __launch_bounds__(256) void k_gate(const ushort4* __restrict__ cur,
                                              const float4* __restrict__ z,
                                              ushort4* __restrict__ gate) {
    gate_body(blockIdx.x, cur, z, gate);
}

// fused: latreduce (32 blocks, first) || spmm (25000 blocks)
__global__ __launch_bounds__(256) void k_fused_sl(const int* __restrict__ row_start,
                                                  const int2* __restrict__ csr,
                                                  const u16* __restrict__ gate,
                                                  float* __restrict__ out0,
                                                  const float* __restrict__ part,
                                                  float* __restrict__ lat) {
    int bid = blockIdx.x;
    if (bid < 32) latreduce_body(bid, part, lat);
    else          spmm_body(bid - 32, row_start, csr, gate, out0);
}

// fused layer-1: gate1 || latpart1. period 9 = {8 gate, 1 latpart}
__global__ __launch_bounds__(256) void k_fused1(const ushort4* __restrict__ cur4,
                                                const float4* __restrict__ z,
                                                ushort4* __restrict__ gate,
                                                const u16* __restrict__ cur,
                                                const u16* __restrict__ hyp,
                                                float* __restrict__ part) {
    int bid = blockIdx.x;
    int p = bid % 9, q = bid / 9;
    if (p < 8) {
        int ch = q * 8 + p;
        if (ch >= SCB) return;
        gate_body(ch, cur4, z, gate);
    } else {
        int uu = q;
        if (uu >= LPB) return;
        latpart_body(uu >> 1, uu & 1, cur, hyp, part);
    }
}

// hyperLat = leaky(hyp @ lat); outL (fp32) = hyperLat; cur (bf16) = hyperLat + tem
__global__ __launch_bounds__(256) void k_hyperlat(const u16* __restrict__ hyp,
                                                  const float* __restrict__ lat,
                                                  const float* __restrict__ tem0,
                                                  float* __restrict__ outL,
                                                  u16* __restrict__ cur) {
    __shared__ float lds[HHY * DD];   // 32 KB
    int t = threadIdx.x;
    for (int i = t; i < HHY * DD; i += 256) lds[i] = lat[i];
    __syncthreads();
    int w = t >> 6, d = t & 63;
    int r0 = blockIdx.x * 16 + w * 4;
    float acc[4] = {0.f, 0.f, 0.f, 0.f};
    for (int h0 = 0; h0 < HHY; h0 += 8) {
        u16 hr[4][8];
#pragma unroll
        for (int r = 0; r < 4; r++) {
            const ushort4* pp = (const ushort4*)(hyp + (size_t)(r0 + r) * HHY + h0);
            ushort4 a = pp[0], b = pp[1];
            hr[r][0] = a.x; hr[r][1] = a.y; hr[r][2] = a.z; hr[r][3] = a.w;
            hr[r][4] = b.x; hr[r][5] = b.y; hr[r][6] = b.z; hr[r][7] = b.w;
        }
#pragma unroll
        for (int j = 0; j < 8; j++) {
            float lv = lds[(h0 + j) * DD + d];
#pragma unroll
            for (int r = 0; r < 4; r++) acc[r] += us2f(hr[r][j]) * lv;
        }
    }
#pragma unroll
    for (int r = 0; r < 4; r++) {
        size_t off = (size_t)(r0 + r) * DD + d;
        float hl = lrelu(acc[r]);
        float tem = tem0[off];
        outL[off] = hl;                 // fp32 output
        cur[off] = f2us(hl + tem);      // bf16 intermediate for next layer
    }
}

// ---------------- launch ----------------

extern "C" void kernel_launch(void* const* d_in, const int* in_sizes, int n_in,
                              void* d_out, int out_size, void* d_ws, size_t ws_size,
                              hipStream_t stream) {
    const int*   rows  = (const int*)d_in[0];    // int32
    const int*   cols  = (const int*)d_in[1];    // int32
    const float* vals  = (const float*)d_in[2];  // fp32
    const float* uEmb  = (const float*)d_in[3];  // fp32
    const float* iEmb  = (const float*)d_in[4];  // fp32
    const float* Hyper = (const float*)d_in[5];  // fp32
    const float* zishi = (const float*)d_in[6];  // fp32
    // d_in[7] = keepRate (==1, static python branch) -> unused

    float* out = (float*)d_out;                  // fp32 output, [3, NN, DD]

    char* ws = (char*)d_ws;
    int2*  csr       = (int2*)(ws + 0);                 // 12,800,000
    int*   row_start = (int*)(ws + 12800000);           //    400,128 (padded)
    u16*   hyp       = (u16*)(ws + 14000128);           // 25,600,000
    u16*   cur       = (u16*)(ws + 39600128);           // 12,800,000
    float* lat       = (float*)(ws + 52400128);         //     32,768
    int*   bsum      = (int*)(ws + 52432896);           //      1,564 -> end 52,434,460

    // Scratch aliased onto d_out's slab2 (bytes 51.2MB..76.8MB of out, 25.6 MB):
    //   ranks  (int,  6.4 MB) @ [0, 6.4M):     written k_hp_ah, last read k_pos.
    //   pos    (int,  6.4 MB) @ [6.4M,12.8M):  written k_pos,  last read k_fused0.
    //   counts (int, padded, 6.4 MB) @ [12.8M,19.2M): memset -> k_hp_ah(atomics) ->
    //                                          blocksum/scanfinal(read); dead before
    //                                          k_fused0 writes part over it.
    //   gate   (bf16, 12.8 MB) @ [0, 12.8M):   written k_gate / k_fused1 (ranks+pos dead),
    //                                          last read k_fused_sl of same layer.
    //   part   (fp32, 12.58 MB) @ [12.8M, 25.4M): written k_fused0/k_fused1,
    //                                          last read k_fused_sl of same layer.
    // Final k_hyperlat(l=1) writes hyperLat2 over the whole slab last.
    char*  slab2  = (char*)(out + (size_t)2 * NN * DD);
    int*   ranks  = (int*)slab2;
    int*   pos    = (int*)(slab2 + 6400000);
    int*   counts = (int*)(slab2 + 12800000);
    u16*   gate   = (u16*)slab2;
    float* part   = (float*)(slab2 + 12800000);

    // CSR build + embeds prep + allhyper (fused)
    hipMemsetAsync(counts, 0, (size_t)NN * CPAD * sizeof(int), stream);
    k_hp_ah<<<3 * SCB, 256, 0, stream>>>(rows, counts, ranks,
                                         (const float4*)uEmb, (const float4*)iEmb,
                                         (ushort4*)cur, Hyper, hyp);
    k_blocksum<<<NSB, 256, 0, stream>>>(counts, bsum);
    k_scanb<<<1, 512, 0, stream>>>(bsum);
    k_scanfinal<<<NSB, 256, 0, stream>>>(counts, bsum, row_start);
    k_pos<<<SCB, 256, 0, stream>>>(rows, ranks, row_start, pos);

    float* out0 = out;  // tem slab (layer-2 spmm overwrites it, matching reference)

    // ---- layer 0 ----
    k_fused0<<<LPB + 8 * 3125, 256, 0, stream>>>(pos, cols, vals, csr, cur, hyp, part);
    k_gate<<<SCB, 256, 0, stream>>>((const ushort4*)cur, (const float4*)zishi, (ushort4*)gate);
    k_fused_sl<<<NN / 4 + 32, 256, 0, stream>>>(row_start, csr, gate, out0, part, lat);
    k_hyperlat<<<NN / 16, 256, 0, stream>>>(hyp, lat, out0, out + (size_t)1 * NN * DD, cur);

    // ---- layer 1 ----
    k_fused1<<<9 * 782, 256, 0, stream>>>((const ushort4*)cur, (const float4*)zishi, (ushort4*)gate,
                                          cur, hyp, part);
    k_fused_sl<<<NN / 4 + 32, 256, 0, stream>>>(row_start, csr, gate, out0, part, lat);
    k_hyperlat<<<NN / 16, 256, 0, stream>>>(hyp, lat, out0, out + (size_t)2 * NN * DD, cur);
}

// Round 9
// 678.627 us; speedup vs baseline: 1.1147x; 1.1147x over previous
//
#include <hip/hip_runtime.h>
#include <hip/hip_bf16.h>

typedef unsigned short u16;

#define NN    100000     // total nodes
#define NU    50000      // users
#define DD    64         // latdim
#define HHY   128        // hyperNum
#define EE    1600000    // nnz
#define NCHK  384        // split-K chunks for lat (part = 12.58 MB, fits slab2 upper half)
#define CROWS 261        // ceil(NN/NCHK)
#define NSB   391        // ceil(NN/256) scan blocks
#define SCB   6250       // scatter / gate / prep chunk count (EE/256)
#define LPB   768        // latpart flat blocks (NCHK chunks x 2 h-halves)
#define BUCKW 400000     // CSR bucket width in entries (EE/4) = 3.2 MB, fits per-XCD L2

__device__ __forceinline__ float us2f(u16 u) {
    union { unsigned int i; float f; } v; v.i = ((unsigned int)u) << 16; return v.f;
}
__device__ __forceinline__ u16 f2us(float f) {
    __hip_bfloat16 b = __float2bfloat16(f);
    return *reinterpret_cast<u16*>(&b);
}
__device__ __forceinline__ float lrelu(float x) { return x > 0.f ? x : 0.5f * x; }

// ================= device bodies (shared by fused wrappers) =================

// allhyper for 16 rows/block, Hyper staged in LDS, 2 rows per thread.
// LDS traffic: 1 float4 per d feeds 8 FMAs (2 rows x 4 h) -> 2x reuse vs L1 path,
// and LDS BW (~69 TB/s agg) >> L1. Embeds preloaded per 32-d half (64 VGPR).
__device__ __forceinline__ void allhyper_body(int ab, float* hlds,
        const float4* __restrict__ u, const float4* __restrict__ it,
        const float* __restrict__ Hyper, u16* __restrict__ hyp) {
    int t = threadIdx.x;
    // stage Hyper[64][128] fp32 (2048 float4) into LDS, coalesced
    const float4* hsrc = (const float4*)Hyper;
    float4* hdst = (float4*)hlds;
#pragma unroll
    for (int i = 0; i < 8; i++) hdst[i * 256 + t] = hsrc[i * 256 + t];
    __syncthreads();
    int hg = t & 31;                       // 32 groups of 4 h
    int rs = t >> 5;                       // 8 row-pair slots
    int n0 = ab * 16 + rs * 2;             // rows n0, n0+1 (16 | NN, always in range)
    int n1 = n0 + 1;
    const float4* s0 = (n0 < NU) ? (u + (size_t)n0 * 16) : (it + (size_t)(n0 - NU) * 16);
    const float4* s1 = (n1 < NU) ? (u + (size_t)n1 * 16) : (it + (size_t)(n1 - NU) * 16);
    float a00 = 0.f, a01 = 0.f, a02 = 0.f, a03 = 0.f;
    float a10 = 0.f, a11 = 0.f, a12 = 0.f, a13 = 0.f;
#pragma unroll
    for (int half = 0; half < 2; half++) {
        float4 e0[8], e1[8];
#pragma unroll
        for (int i = 0; i < 8; i++) { e0[i] = s0[half * 8 + i]; e1[i] = s1[half * 8 + i]; }
#pragma unroll
        for (int i = 0; i < 8; i++) {
            float ev0[4] = { e0[i].x, e0[i].y, e0[i].z, e0[i].w };
            float ev1[4] = { e1[i].x, e1[i].y, e1[i].z, e1[i].w };
#pragma unroll
            for (int k = 0; k < 4; k++) {
                int d = half * 32 + i * 4 + k;
                float4 hq = *(const float4*)(hlds + d * HHY + hg * 4);
                a00 += ev0[k] * hq.x; a01 += ev0[k] * hq.y;
                a02 += ev0[k] * hq.z; a03 += ev0[k] * hq.w;
                a10 += ev1[k] * hq.x; a11 += ev1[k] * hq.y;
                a12 += ev1[k] * hq.z; a13 += ev1[k] * hq.w;
            }
        }
    }
    u16* o0 = hyp + (size_t)n0 * HHY + hg * 4;
    o0[0] = f2us(a00); o0[1] = f2us(a01); o0[2] = f2us(a02); o0[3] = f2us(a03);
    u16* o1 = hyp + (size_t)n1 * HHY + hg * 4;
    o1[0] = f2us(a10); o1[1] = f2us(a11); o1[2] = f2us(a12); o1[3] = f2us(a13);
}

__device__ __forceinline__ void latpart_body(int chunk, int yy,
        const u16* __restrict__ cur, const u16* __restrict__ hyp,
        float* __restrict__ part) {
    int t = threadIdx.x;
    int w = t >> 6, d = t & 63;
    int h0 = (yy * 4 + w) * 16;
    int c0 = chunk * CROWS;
    int c1 = c0 + CROWS; if (c1 > NN) c1 = NN;
    float acc[16];
#pragma unroll
    for (int j = 0; j < 16; j++) acc[j] = 0.f;
    for (int n = c0; n < c1; n++) {
        float cv = us2f(cur[(size_t)n * DD + d]);
        const ushort4* hp = (const ushort4*)(hyp + (size_t)n * HHY + h0);
        u16 ha[16];
        *(ushort4*)(ha + 0)  = hp[0];
        *(ushort4*)(ha + 4)  = hp[1];
        *(ushort4*)(ha + 8)  = hp[2];
        *(ushort4*)(ha + 12) = hp[3];
#pragma unroll
        for (int j = 0; j < 16; j++) acc[j] += us2f(ha[j]) * cv;
    }
#pragma unroll
    for (int j = 0; j < 16; j++)
        part[((size_t)chunk * HHY + h0 + j) * DD + d] = acc[j];
}

__device__ __forceinline__ void gate_body(int ch,
        const ushort4* __restrict__ cur, const float4* __restrict__ z,
        ushort4* __restrict__ gate) {
    int idx = ch * 256 + threadIdx.x;      // ch < SCB -> idx < NN*DD/4
    ushort4 c = cur[idx];
    float4 zz = z[idx];
    ushort4 o;
    o.x = f2us(us2f(c.x) * (2.f / (1.f + __expf(-zz.x)) - 1.f));
    o.y = f2us(us2f(c.y) * (2.f / (1.f + __expf(-zz.y)) - 1.f));
    o.z = f2us(us2f(c.z) * (2.f / (1.f + __expf(-zz.z)) - 1.f));
    o.w = f2us(us2f(c.w) * (2.f / (1.f + __expf(-zz.w)) - 1.f));
    gate[idx] = o;
}

// bucketed scatter: block handles (chunk, bucket); writes only edges whose CSR
// position falls in its bucket's 3.2 MB window (XCD-local L2 merging).
__device__ __forceinline__ void scatter_body(int chunk, int bucket,
        const int* __restrict__ pos,
        const int* __restrict__ cols, const float* __restrict__ vals,
        int2* __restrict__ csr) {
    int e = chunk * 256 + threadIdx.x;     // < EE
    int p = pos[e];
    if ((unsigned)p / (unsigned)BUCKW == (unsigned)bucket) {
        csr[p] = make_int2(cols[e], __float_as_int(vals[e]));
    }
}

__device__ __forceinline__ void spmm_body(int b,
        const int* __restrict__ row_start, const int2* __restrict__ csr,
        const u16* __restrict__ gate, float* __restrict__ out0) {
    int w = threadIdx.x >> 6, d = threadIdx.x & 63;
    int row = b * 4 + w;                   // b < NN/4 -> row < NN
    int s = row_start[row], e = row_start[row + 1];
    float a0 = 0.f, a1 = 0.f, a2 = 0.f, a3 = 0.f;
    float a4 = 0.f, a5 = 0.f, a6 = 0.f, a7 = 0.f;
    int j = s;
    for (; j + 8 <= e; j += 8) {
        int2 c0 = csr[j],     c1 = csr[j + 1], c2 = csr[j + 2], c3 = csr[j + 3];
        int2 c4 = csr[j + 4], c5 = csr[j + 5], c6 = csr[j + 6], c7 = csr[j + 7];
        float g0 = us2f(gate[(size_t)c0.x * DD + d]);
        float g1 = us2f(gate[(size_t)c1.x * DD + d]);
        float g2 = us2f(gate[(size_t)c2.x * DD + d]);
        float g3 = us2f(gate[(size_t)c3.x * DD + d]);
        float g4 = us2f(gate[(size_t)c4.x * DD + d]);
        float g5 = us2f(gate[(size_t)c5.x * DD + d]);
        float g6 = us2f(gate[(size_t)c6.x * DD + d]);
        float g7 = us2f(gate[(size_t)c7.x * DD + d]);
        a0 += __int_as_float(c0.y) * g0;
        a1 += __int_as_float(c1.y) * g1;
        a2 += __int_as_float(c2.y) * g2;
        a3 += __int_as_float(c3.y) * g3;
        a4 += __int_as_float(c4.y) * g4;
        a5 += __int_as_float(c5.y) * g5;
        a6 += __int_as_float(c6.y) * g6;
        a7 += __int_as_float(c7.y) * g7;
    }
    for (; j + 4 <= e; j += 4) {
        int2 c0 = csr[j], c1 = csr[j + 1], c2 = csr[j + 2], c3 = csr[j + 3];
        float g0 = us2f(gate[(size_t)c0.x * DD + d]);
        float g1 = us2f(gate[(size_t)c1.x * DD + d]);
        float g2 = us2f(gate[(size_t)c2.x * DD + d]);
        float g3 = us2f(gate[(size_t)c3.x * DD + d]);
        a0 += __int_as_float(c0.y) * g0;
        a1 += __int_as_float(c1.y) * g1;
        a2 += __int_as_float(c2.y) * g2;
        a3 += __int_as_float(c3.y) * g3;
    }
    for (; j < e; j++) {
        int2 cv = csr[j];
        a0 += __int_as_float(cv.y) * us2f(gate[(size_t)cv.x * DD + d]);
    }
    float acc = ((a0 + a1) + (a2 + a3)) + ((a4 + a5) + (a6 + a7));
    out0[(size_t)row * DD + d] = lrelu(acc);
}

__device__ __forceinline__ void latreduce_body(int lb,
        const float* __restrict__ part, float* __restrict__ lat) {
    int idx = lb * 256 + threadIdx.x;      // h*64+d, 8192 total
    float s0 = 0.f, s1 = 0.f, s2 = 0.f, s3 = 0.f;
    for (int c = 0; c < NCHK; c += 4) {
        s0 += part[(size_t)(c + 0) * HHY * DD + idx];
        s1 += part[(size_t)(c + 1) * HHY * DD + idx];
        s2 += part[(size_t)(c + 2) * HHY * DD + idx];
        s3 += part[(size_t)(c + 3) * HHY * DD + idx];
    }
    lat[idx] = lrelu((s0 + s1) + (s2 + s3));
}

// ================= kernels =================

// fused: histprep (prep embeds0->bf16 cur, hist counts+ranks) || allhyper (LDS-staged)
// grid = 2*SCB; even blocks prep/hist (6250), odd blocks allhyper (6250 x 16 rows)
__global__ __launch_bounds__(256) void k_hp_ah(const int* __restrict__ rows,
                                               int* __restrict__ cnt,
                                               int* __restrict__ ranks,
                                               const float4* __restrict__ u,
                                               const float4* __restrict__ it,
                                               ushort4* __restrict__ cur,
                                               const float* __restrict__ Hyper,
                                               u16* __restrict__ hyp) {
    __shared__ float hlds[DD * HHY];       // 32 KB (allhyper branch only)
    int bid = blockIdx.x;
    int p = bid & 1, q = bid >> 1;
    if (p == 0) {
        int e = q * 256 + threadIdx.x;     // < EE
        const int HALF = NU * DD / 4;      // 800000
        float4 f = (e < HALF) ? u[e] : it[e - HALF];
        ushort4 o; o.x = f2us(f.x); o.y = f2us(f.y); o.z = f2us(f.z); o.w = f2us(f.w);
        cur[e] = o;
        ranks[e] = atomicAdd(&cnt[rows[e]], 1);
    } else {
        allhyper_body(q, hlds, u, it, Hyper, hyp);
    }
}

// phase 1: per-block sums of cnt (256 counts per block)
__global__ __launch_bounds__(256) void k_blocksum(const int* __restrict__ cnt,
                                                  int* __restrict__ bsum) {
    __shared__ int s[256];
    int t = threadIdx.x;
    int i = blockIdx.x * 256 + t;
    s[t] = (i < NN) ? cnt[i] : 0;
    __syncthreads();
    for (int off = 128; off > 0; off >>= 1) {
        if (t < off) s[t] += s[t + off];
        __syncthreads();
    }
    if (t == 0) bsum[blockIdx.x] = s[0];
}

// phase 2: exclusive scan of the 391 block sums (single small block)
__global__ __launch_bounds__(512) void k_scanb(int* __restrict__ bsum) {
    __shared__ int s[512];
    int t = threadIdx.x;
    int v = (t < NSB) ? bsum[t] : 0;
    s[t] = v;
    __syncthreads();
    for (int off = 1; off < 512; off <<= 1) {
        int add = (t >= off) ? s[t - off] : 0;
        __syncthreads();
        s[t] += add;
        __syncthreads();
    }
    if (t < NSB) bsum[t] = s[t] - v;   // exclusive
}

// phase 3: block-local scan + block offset -> row_start
__global__ __launch_bounds__(256) void k_scanfinal(const int* __restrict__ cnt,
                                                   const int* __restrict__ bsum,
                                                   int* __restrict__ row_start) {
    __shared__ int s[256];
    int t = threadIdx.x;
    int i = blockIdx.x * 256 + t;
    int v = (i < NN) ? cnt[i] : 0;
    s[t] = v;
    __syncthreads();
    for (int off = 1; off < 256; off <<= 1) {
        int add = (t >= off) ? s[t - off] : 0;
        __syncthreads();
        s[t] += add;
        __syncthreads();
    }
    int excl = s[t] - v + bsum[blockIdx.x];
    if (i < NN) row_start[i] = excl;
    if (i == NN - 1) row_start[NN] = excl + v;   // total nnz
}

// pos[e] = final CSR position of edge e (coalesced; row_start gather is L2-resident)
__global__ __launch_bounds__(256) void k_pos(const int* __restrict__ rows,
                                             const int* __restrict__ ranks,
                                             const int* __restrict__ row_start,
                                             int* __restrict__ pos) {
    int e = blockIdx.x * 256 + threadIdx.x;   // grid = SCB -> e < EE
    pos[e] = row_start[rows[e]] + ranks[e];
}

// fused layer-0: latpart0 (first 768 long blocks) || XCD-bucketed scatter.
__global__ __launch_bounds__(256) void k_fused0(const int* __restrict__ pos,
                                                const int* __restrict__ cols,
                                                const float* __restrict__ vals,
                                                int2* __restrict__ csr,
                                                const u16* __restrict__ cur,
                                                const u16* __restrict__ hyp,
                                                float* __restrict__ part) {
    int bid = blockIdx.x;
    if (bid < LPB) {
        latpart_body(bid >> 1, bid & 1, cur, hyp, part);
    } else {
        int sid = bid - LPB;               // LPB%8==0 so sid%8 == bid%8 == XCD
        int xcd = sid & 7;
        int bucket = xcd & 3;
        int chunk = (sid >> 3) * 2 + (xcd >> 2);   // 0..6249
        scatter_body(chunk, bucket, pos, cols, vals, csr);
    }
}

// standalone gate (layer 0 only; layer 1's gate is fused with latpart1)
__global__ __launch_bounds__(256) void k_gate(const ushort4* __restrict__ cur,
                                              const float4* __restrict__ z,
                                              ushort4* __restrict__ gate) {
    gate_body(blockIdx.x, cur, z, gate);
}

// fused: latreduce (32 blocks, first) || spmm (25000 blocks)
__global__ __launch_bounds__(256) void k_fused_sl(const int* __restrict__ row_start,
                                                  const int2* __restrict__ csr,
                                                  const u16* __restrict__ gate,
                                                  float* __restrict__ out0,
                                                  const float* __restrict__ part,
                                                  float* __restrict__ lat) {
    int bid = blockIdx.x;
    if (bid < 32) latreduce_body(bid, part, lat);
    else          spmm_body(bid - 32, row_start, csr, gate, out0);
}

// fused layer-1: gate1 || latpart1. period 9 = {8 gate, 1 latpart}
__global__ __launch_bounds__(256) void k_fused1(const ushort4* __restrict__ cur4,
                                                const float4* __restrict__ z,
                                                ushort4* __restrict__ gate,
                                                const u16* __restrict__ cur,
                                                const u16* __restrict__ hyp,
                                                float* __restrict__ part) {
    int bid = blockIdx.x;
    int p = bid % 9, q = bid / 9;
    if (p < 8) {
        int ch = q * 8 + p;
        if (ch >= SCB) return;
        gate_body(ch, cur4, z, gate);
    } else {
        int uu = q;
        if (uu >= LPB) return;
        latpart_body(uu >> 1, uu & 1, cur, hyp, part);
    }
}

// hyperLat = leaky(hyp @ lat); outL (fp32) = hyperLat; cur (bf16) = hyperLat + tem
__global__ __launch_bounds__(256) void k_hyperlat(const u16* __restrict__ hyp,
                                                  const float* __restrict__ lat,
                                                  const float* __restrict__ tem0,
                                                  float* __restrict__ outL,
                                                  u16* __restrict__ cur) {
    __shared__ float lds[HHY * DD];   // 32 KB
    int t = threadIdx.x;
    for (int i = t; i < HHY * DD; i += 256) lds[i] = lat[i];
    __syncthreads();
    int w = t >> 6, d = t & 63;
    int r0 = blockIdx.x * 16 + w * 4;
    float acc[4] = {0.f, 0.f, 0.f, 0.f};
    for (int h0 = 0; h0 < HHY; h0 += 8) {
        u16 hr[4][8];
#pragma unroll
        for (int r = 0; r < 4; r++) {
            const ushort4* pp = (const ushort4*)(hyp + (size_t)(r0 + r) * HHY + h0);
            ushort4 a = pp[0], b = pp[1];
            hr[r][0] = a.x; hr[r][1] = a.y; hr[r][2] = a.z; hr[r][3] = a.w;
            hr[r][4] = b.x; hr[r][5] = b.y; hr[r][6] = b.z; hr[r][7] = b.w;
        }
#pragma unroll
        for (int j = 0; j < 8; j++) {
            float lv = lds[(h0 + j) * DD + d];
#pragma unroll
            for (int r = 0; r < 4; r++) acc[r] += us2f(hr[r][j]) * lv;
        }
    }
#pragma unroll
    for (int r = 0; r < 4; r++) {
        size_t off = (size_t)(r0 + r) * DD + d;
        float hl = lrelu(acc[r]);
        float tem = tem0[off];
        outL[off] = hl;                 // fp32 output
        cur[off] = f2us(hl + tem);      // bf16 intermediate for next layer
    }
}

// ---------------- launch ----------------

extern "C" void kernel_launch(void* const* d_in, const int* in_sizes, int n_in,
                              void* d_out, int out_size, void* d_ws, size_t ws_size,
                              hipStream_t stream) {
    const int*   rows  = (const int*)d_in[0];    // int32
    const int*   cols  = (const int*)d_in[1];    // int32
    const float* vals  = (const float*)d_in[2];  // fp32
    const float* uEmb  = (const float*)d_in[3];  // fp32
    const float* iEmb  = (const float*)d_in[4];  // fp32
    const float* Hyper = (const float*)d_in[5];  // fp32
    const float* zishi = (const float*)d_in[6];  // fp32
    // d_in[7] = keepRate (==1, static python branch) -> unused

    float* out = (float*)d_out;                  // fp32 output, [3, NN, DD]

    char* ws = (char*)d_ws;
    int2*  csr       = (int2*)(ws + 0);                 // 12,800,000
    int*   row_start = (int*)(ws + 12800000);           //    400,128 (padded)
    int*   counts    = (int*)(ws + 13600128);           //    400,000
    u16*   hyp       = (u16*)(ws + 14000128);           // 25,600,000
    u16*   cur       = (u16*)(ws + 39600128);           // 12,800,000
    float* lat       = (float*)(ws + 52400128);         //     32,768
    int*   bsum      = (int*)(ws + 52432896);           //      1,564 -> end 52,434,460

    // Scratch aliased onto d_out's slab2 (bytes 51.2MB..76.8MB of out, 25.6 MB):
    //   ranks (int,  6.4 MB) @ [0, 6.4M):    written k_hp_ah, last read k_pos.
    //   pos   (int,  6.4 MB) @ [6.4M,12.8M): written k_pos,  last read k_fused0.
    //   gate  (bf16, 12.8 MB) @ [0, 12.8M):  written k_gate / k_fused1 (ranks+pos dead),
    //                                        last read k_fused_sl of same layer.
    //   part  (fp32, 12.58 MB) @ [12.8M, 25.4M): written k_fused0/k_fused1,
    //                                        last read k_fused_sl of same layer.
    // Final k_hyperlat(l=1) writes hyperLat2 over the whole slab last.
    char*  slab2 = (char*)(out + (size_t)2 * NN * DD);
    int*   ranks = (int*)slab2;
    int*   pos   = (int*)(slab2 + 6400000);
    u16*   gate  = (u16*)slab2;
    float* part  = (float*)(slab2 + 12800000);

    // CSR build + embeds prep + allhyper (fused)
    hipMemsetAsync(counts, 0, NN * sizeof(int), stream);
    k_hp_ah<<<2 * SCB, 256, 0, stream>>>(rows, counts, ranks,
                                         (const float4*)uEmb, (const float4*)iEmb,
                                         (ushort4*)cur, Hyper, hyp);
    k_blocksum<<<NSB, 256, 0, stream>>>(counts, bsum);
    k_scanb<<<1, 512, 0, stream>>>(bsum);
    k_scanfinal<<<NSB, 256, 0, stream>>>(counts, bsum, row_start);
    k_pos<<<SCB, 256, 0, stream>>>(rows, ranks, row_start, pos);

    float* out0 = out;  // tem slab (layer-2 spmm overwrites it, matching reference)

    // ---- layer 0 ----
    k_fused0<<<LPB + 8 * 3125, 256, 0, stream>>>(pos, cols, vals, csr, cur, hyp, part);
    k_gate<<<SCB, 256, 0, stream>>>((const ushort4*)cur, (const float4*)zishi, (ushort4*)gate);
    k_fused_sl<<<NN / 4 + 32, 256, 0, stream>>>(row_start, csr, gate, out0, part, lat);
    k_hyperlat<<<NN / 16, 256, 0, stream>>>(hyp, lat, out0, out + (size_t)1 * NN * DD, cur);

    // ---- layer 1 ----
    k_fused1<<<9 * 782, 256, 0, stream>>>((const ushort4*)cur, (const float4*)zishi, (ushort4*)gate,
                                          cur, hyp, part);
    k_fused_sl<<<NN / 4 + 32, 256, 0, stream>>>(row_start, csr, gate, out0, part, lat);
    k_hyperlat<<<NN / 16, 256, 0, stream>>>(hyp, lat, out0, out + (size_t)2 * NN * DD, cur);
}

// Round 10
// 614.260 us; speedup vs baseline: 1.2315x; 1.1048x over previous
//
#include <hip/hip_runtime.h>
#include <hip/hip_bf16.h>

typedef unsigned short u16;

#define NN    100000     // total nodes
#define NU    50000      // users
#define DD    64         // latdim
#define HHY   128        // hyperNum
#define EE    1600000    // nnz
#define NCHK  384        // split-K chunks for lat (part = 12.58 MB, fits slab2 upper half)
#define CROWS 261        // ceil(NN/NCHK)
#define NSB   391        // ceil(NN/256) scan blocks
#define SCB   6250       // scatter / gate / prep chunk count (EE/256)
#define LPB   768        // latpart flat blocks (NCHK chunks x 2 h-halves)
#define BUCKW 400000     // CSR bucket width in entries (EE/4) = 3.2 MB, fits per-XCD L2

__device__ __forceinline__ float us2f(u16 u) {
    union { unsigned int i; float f; } v; v.i = ((unsigned int)u) << 16; return v.f;
}
__device__ __forceinline__ u16 f2us(float f) {
    __hip_bfloat16 b = __float2bfloat16(f);
    return *reinterpret_cast<u16*>(&b);
}
__device__ __forceinline__ float lrelu(float x) { return x > 0.f ? x : 0.5f * x; }

// ================= device bodies (shared by fused wrappers) =================

// allhyper for 16 rows/block, Hyper staged in LDS, 2 rows per thread.
__device__ __forceinline__ void allhyper_body(int ab, float* hlds,
        const float4* __restrict__ u, const float4* __restrict__ it,
        const float* __restrict__ Hyper, u16* __restrict__ hyp) {
    int t = threadIdx.x;
    // stage Hyper[64][128] fp32 (2048 float4) into LDS, coalesced
    const float4* hsrc = (const float4*)Hyper;
    float4* hdst = (float4*)hlds;
#pragma unroll
    for (int i = 0; i < 8; i++) hdst[i * 256 + t] = hsrc[i * 256 + t];
    __syncthreads();
    int hg = t & 31;                       // 32 groups of 4 h
    int rs = t >> 5;                       // 8 row-pair slots
    int n0 = ab * 16 + rs * 2;             // rows n0, n0+1
    int n1 = n0 + 1;
    const float4* s0 = (n0 < NU) ? (u + (size_t)n0 * 16) : (it + (size_t)(n0 - NU) * 16);
    const float4* s1 = (n1 < NU) ? (u + (size_t)n1 * 16) : (it + (size_t)(n1 - NU) * 16);
    float a00 = 0.f, a01 = 0.f, a02 = 0.f, a03 = 0.f;
    float a10 = 0.f, a11 = 0.f, a12 = 0.f, a13 = 0.f;
#pragma unroll
    for (int half = 0; half < 2; half++) {
        float4 e0[8], e1[8];
#pragma unroll
        for (int i = 0; i < 8; i++) { e0[i] = s0[half * 8 + i]; e1[i] = s1[half * 8 + i]; }
#pragma unroll
        for (int i = 0; i < 8; i++) {
            float ev0[4] = { e0[i].x, e0[i].y, e0[i].z, e0[i].w };
            float ev1[4] = { e1[i].x, e1[i].y, e1[i].z, e1[i].w };
#pragma unroll
            for (int k = 0; k < 4; k++) {
                int d = half * 32 + i * 4 + k;
                float4 hq = *(const float4*)(hlds + d * HHY + hg * 4);
                a00 += ev0[k] * hq.x; a01 += ev0[k] * hq.y;
                a02 += ev0[k] * hq.z; a03 += ev0[k] * hq.w;
                a10 += ev1[k] * hq.x; a11 += ev1[k] * hq.y;
                a12 += ev1[k] * hq.z; a13 += ev1[k] * hq.w;
            }
        }
    }
    u16* o0 = hyp + (size_t)n0 * HHY + hg * 4;
    o0[0] = f2us(a00); o0[1] = f2us(a01); o0[2] = f2us(a02); o0[3] = f2us(a03);
    u16* o1 = hyp + (size_t)n1 * HHY + hg * 4;
    o1[0] = f2us(a10); o1[1] = f2us(a11); o1[2] = f2us(a12); o1[3] = f2us(a13);
}

// latpart: x4 n-unroll -> 20 independent loads in flight per thread (MLP)
__device__ __forceinline__ void latpart_body(int chunk, int yy,
        const u16* __restrict__ cur, const u16* __restrict__ hyp,
        float* __restrict__ part) {
    int t = threadIdx.x;
    int w = t >> 6, d = t & 63;
    int h0 = (yy * 4 + w) * 16;
    int c0 = chunk * CROWS;
    int c1 = c0 + CROWS; if (c1 > NN) c1 = NN;
    float acc[16];
#pragma unroll
    for (int j = 0; j < 16; j++) acc[j] = 0.f;
    int n = c0;
    for (; n + 4 <= c1; n += 4) {
        const u16* cp = cur + (size_t)n * DD + d;
        u16 ca = cp[0], cb = cp[DD], cc = cp[2 * DD], cd = cp[3 * DD];
        const ushort4* ha4 = (const ushort4*)(hyp + (size_t)n * HHY + h0);
        const ushort4* hb4 = (const ushort4*)(hyp + (size_t)(n + 1) * HHY + h0);
        const ushort4* hc4 = (const ushort4*)(hyp + (size_t)(n + 2) * HHY + h0);
        const ushort4* hd4 = (const ushort4*)(hyp + (size_t)(n + 3) * HHY + h0);
        u16 ua[16], ub[16], uc[16], ud[16];
        *(ushort4*)(ua + 0) = ha4[0]; *(ushort4*)(ua + 4) = ha4[1];
        *(ushort4*)(ua + 8) = ha4[2]; *(ushort4*)(ua + 12) = ha4[3];
        *(ushort4*)(ub + 0) = hb4[0]; *(ushort4*)(ub + 4) = hb4[1];
        *(ushort4*)(ub + 8) = hb4[2]; *(ushort4*)(ub + 12) = hb4[3];
        *(ushort4*)(uc + 0) = hc4[0]; *(ushort4*)(uc + 4) = hc4[1];
        *(ushort4*)(uc + 8) = hc4[2]; *(ushort4*)(uc + 12) = hc4[3];
        *(ushort4*)(ud + 0) = hd4[0]; *(ushort4*)(ud + 4) = hd4[1];
        *(ushort4*)(ud + 8) = hd4[2]; *(ushort4*)(ud + 12) = hd4[3];
        float fa = us2f(ca), fb = us2f(cb), fc = us2f(cc), fd = us2f(cd);
#pragma unroll
        for (int j = 0; j < 16; j++)
            acc[j] += us2f(ua[j]) * fa + us2f(ub[j]) * fb
                    + us2f(uc[j]) * fc + us2f(ud[j]) * fd;
    }
    for (; n < c1; n++) {
        float cv = us2f(cur[(size_t)n * DD + d]);
        const ushort4* hp = (const ushort4*)(hyp + (size_t)n * HHY + h0);
        u16 ha[16];
        *(ushort4*)(ha + 0)  = hp[0];
        *(ushort4*)(ha + 4)  = hp[1];
        *(ushort4*)(ha + 8)  = hp[2];
        *(ushort4*)(ha + 12) = hp[3];
#pragma unroll
        for (int j = 0; j < 16; j++) acc[j] += us2f(ha[j]) * cv;
    }
#pragma unroll
    for (int j = 0; j < 16; j++)
        part[((size_t)chunk * HHY + h0 + j) * DD + d] = acc[j];
}

__device__ __forceinline__ void gate_body(int ch,
        const ushort4* __restrict__ cur, const float4* __restrict__ z,
        ushort4* __restrict__ gate) {
    int idx = ch * 256 + threadIdx.x;      // ch < SCB -> idx < NN*DD/4
    ushort4 c = cur[idx];
    float4 zz = z[idx];
    ushort4 o;
    o.x = f2us(us2f(c.x) * (2.f / (1.f + __expf(-zz.x)) - 1.f));
    o.y = f2us(us2f(c.y) * (2.f / (1.f + __expf(-zz.y)) - 1.f));
    o.z = f2us(us2f(c.z) * (2.f / (1.f + __expf(-zz.z)) - 1.f));
    o.w = f2us(us2f(c.w) * (2.f / (1.f + __expf(-zz.w)) - 1.f));
    gate[idx] = o;
}

// bucketed scatter: block handles (chunk, bucket); writes only edges whose CSR
// position falls in its bucket's 3.2 MB window (XCD-local L2 merging).
__device__ __forceinline__ void scatter_body(int chunk, int bucket,
        const int* __restrict__ pos,
        const int* __restrict__ cols, const float* __restrict__ vals,
        int2* __restrict__ csr) {
    int e = chunk * 256 + threadIdx.x;     // < EE
    int p = pos[e];
    if ((unsigned)p / (unsigned)BUCKW == (unsigned)bucket) {
        csr[p] = make_int2(cols[e], __float_as_int(vals[e]));
    }
}

__device__ __forceinline__ void spmm_body(int b,
        const int* __restrict__ row_start, const int2* __restrict__ csr,
        const u16* __restrict__ gate, float* __restrict__ out0) {
    int w = threadIdx.x >> 6, d = threadIdx.x & 63;
    int row = b * 4 + w;                   // b < NN/4 -> row < NN
    int s = row_start[row], e = row_start[row + 1];
    float a0 = 0.f, a1 = 0.f, a2 = 0.f, a3 = 0.f;
    float a4 = 0.f, a5 = 0.f, a6 = 0.f, a7 = 0.f;
    int j = s;
    for (; j + 8 <= e; j += 8) {
        int2 c0 = csr[j],     c1 = csr[j + 1], c2 = csr[j + 2], c3 = csr[j + 3];
        int2 c4 = csr[j + 4], c5 = csr[j + 5], c6 = csr[j + 6], c7 = csr[j + 7];
        float g0 = us2f(gate[(size_t)c0.x * DD + d]);
        float g1 = us2f(gate[(size_t)c1.x * DD + d]);
        float g2 = us2f(gate[(size_t)c2.x * DD + d]);
        float g3 = us2f(gate[(size_t)c3.x * DD + d]);
        float g4 = us2f(gate[(size_t)c4.x * DD + d]);
        float g5 = us2f(gate[(size_t)c5.x * DD + d]);
        float g6 = us2f(gate[(size_t)c6.x * DD + d]);
        float g7 = us2f(gate[(size_t)c7.x * DD + d]);
        a0 += __int_as_float(c0.y) * g0;
        a1 += __int_as_float(c1.y) * g1;
        a2 += __int_as_float(c2.y) * g2;
        a3 += __int_as_float(c3.y) * g3;
        a4 += __int_as_float(c4.y) * g4;
        a5 += __int_as_float(c5.y) * g5;
        a6 += __int_as_float(c6.y) * g6;
        a7 += __int_as_float(c7.y) * g7;
    }
    for (; j + 4 <= e; j += 4) {
        int2 c0 = csr[j], c1 = csr[j + 1], c2 = csr[j + 2], c3 = csr[j + 3];
        float g0 = us2f(gate[(size_t)c0.x * DD + d]);
        float g1 = us2f(gate[(size_t)c1.x * DD + d]);
        float g2 = us2f(gate[(size_t)c2.x * DD + d]);
        float g3 = us2f(gate[(size_t)c3.x * DD + d]);
        a0 += __int_as_float(c0.y) * g0;
        a1 += __int_as_float(c1.y) * g1;
        a2 += __int_as_float(c2.y) * g2;
        a3 += __int_as_float(c3.y) * g3;
    }
    for (; j < e; j++) {
        int2 cv = csr[j];
        a0 += __int_as_float(cv.y) * us2f(gate[(size_t)cv.x * DD + d]);
    }
    float acc = ((a0 + a1) + (a2 + a3)) + ((a4 + a5) + (a6 + a7));
    out0[(size_t)row * DD + d] = lrelu(acc);
}

__device__ __forceinline__ void latreduce_body(int lb,
        const float* __restrict__ part, float* __restrict__ lat) {
    int idx = lb * 256 + threadIdx.x;      // h*64+d, 8192 total
    float s0 = 0.f, s1 = 0.f, s2 = 0.f, s3 = 0.f;
    for (int c = 0; c < NCHK; c += 4) {
        s0 += part[(size_t)(c + 0) * HHY * DD + idx];
        s1 += part[(size_t)(c + 1) * HHY * DD + idx];
        s2 += part[(size_t)(c + 2) * HHY * DD + idx];
        s3 += part[(size_t)(c + 3) * HHY * DD + idx];
    }
    lat[idx] = lrelu((s0 + s1) + (s2 + s3));
}

// ================= kernels =================

// fused: histprep (prep embeds0->bf16 cur, hist counts+ranks) || allhyper (LDS-staged)
__global__ __launch_bounds__(256) void k_hp_ah(const int* __restrict__ rows,
                                               int* __restrict__ cnt,
                                               int* __restrict__ ranks,
                                               const float4* __restrict__ u,
                                               const float4* __restrict__ it,
                                               ushort4* __restrict__ cur,
                                               const float* __restrict__ Hyper,
                                               u16* __restrict__ hyp) {
    __shared__ float hlds[DD * HHY];       // 32 KB (allhyper branch only)
    int bid = blockIdx.x;
    int p = bid & 1, q = bid >> 1;
    if (p == 0) {
        int e = q * 256 + threadIdx.x;     // < EE
        const int HALF = NU * DD / 4;      // 800000
        float4 f = (e < HALF) ? u[e] : it[e - HALF];
        ushort4 o; o.x = f2us(f.x); o.y = f2us(f.y); o.z = f2us(f.z); o.w = f2us(f.w);
        cur[e] = o;
        ranks[e] = atomicAdd(&cnt[rows[e]], 1);
    } else {
        allhyper_body(q, hlds, u, it, Hyper, hyp);
    }
}

// phase 1: per-block sums of cnt (256 counts per block)
__global__ __launch_bounds__(256) void k_blocksum(const int* __restrict__ cnt,
                                                  int* __restrict__ bsum) {
    __shared__ int s[256];
    int t = threadIdx.x;
    int i = blockIdx.x * 256 + t;
    s[t] = (i < NN) ? cnt[i] : 0;
    __syncthreads();
    for (int off = 128; off > 0; off >>= 1) {
        if (t < off) s[t] += s[t + off];
        __syncthreads();
    }
    if (t == 0) bsum[blockIdx.x] = s[0];
}

// phase 2: exclusive scan of the 391 block sums (single small block)
__global__ __launch_bounds__(512) void k_scanb(int* __restrict__ bsum) {
    __shared__ int s[512];
    int t = threadIdx.x;
    int v = (t < NSB) ? bsum[t] : 0;
    s[t] = v;
    __syncthreads();
    for (int off = 1; off < 512; off <<= 1) {
        int add = (t >= off) ? s[t - off] : 0;
        __syncthreads();
        s[t] += add;
        __syncthreads();
    }
    if (t < NSB) bsum[t] = s[t] - v;   // exclusive
}

// phase 3: block-local scan + block offset -> row_start
__global__ __launch_bounds__(256) void k_scanfinal(const int* __restrict__ cnt,
                                                   const int* __restrict__ bsum,
                                                   int* __restrict__ row_start) {
    __shared__ int s[256];
    int t = threadIdx.x;
    int i = blockIdx.x * 256 + t;
    int v = (i < NN) ? cnt[i] : 0;
    s[t] = v;
    __syncthreads();
    for (int off = 1; off < 256; off <<= 1) {
        int add = (t >= off) ? s[t - off] : 0;
        __syncthreads();
        s[t] += add;
        __syncthreads();
    }
    int excl = s[t] - v + bsum[blockIdx.x];
    if (i < NN) row_start[i] = excl;
    if (i == NN - 1) row_start[NN] = excl + v;   // total nnz
}

// pos[e] = final CSR position of edge e (coalesced; row_start gather is L2-resident)
__global__ __launch_bounds__(256) void k_pos(const int* __restrict__ rows,
                                             const int* __restrict__ ranks,
                                             const int* __restrict__ row_start,
                                             int* __restrict__ pos) {
    int e = blockIdx.x * 256 + threadIdx.x;   // grid = SCB -> e < EE
    pos[e] = row_start[rows[e]] + ranks[e];
}

// fused layer-0: latpart0 (first 768 long blocks) || XCD-bucketed scatter.
__global__ __launch_bounds__(256) void k_fused0(const int* __restrict__ pos,
                                                const int* __restrict__ cols,
                                                const float* __restrict__ vals,
                                                int2* __restrict__ csr,
                                                const u16* __restrict__ cur,
                                                const u16* __restrict__ hyp,
                                                float* __restrict__ part) {
    int bid = blockIdx.x;
    if (bid < LPB) {
        latpart_body(bid >> 1, bid & 1, cur, hyp, part);
    } else {
        int sid = bid - LPB;               // LPB%8==0 so sid%8 == bid%8 == XCD
        int xcd = sid & 7;
        int bucket = xcd & 3;
        int chunk = (sid >> 3) * 2 + (xcd >> 2);   // 0..6249
        scatter_body(chunk, bucket, pos, cols, vals, csr);
    }
}

// standalone gate (layer 0 only; layer 1's gate is fused into k_hyperlat(l0))
__global__ __launch_bounds__(256) void k_gate(const ushort4* __restrict__ cur,
                                              const float4* __restrict__ z,
                                              ushort4* __restrict__ gate) {
    gate_body(blockIdx.x, cur, z, gate);
}

// fused: latreduce (32 blocks, first) || spmm (25000 blocks)
__global__ __launch_bounds__(256) void k_fused_sl(const int* __restrict__ row_start,
                                                  const int2* __restrict__ csr,
                                                  const u16* __restrict__ gate,
                                                  float* __restrict__ out0,
                                                  const float* __restrict__ part,
                                                  float* __restrict__ lat) {
    int bid = blockIdx.x;
    if (bid < 32) latreduce_body(bid, part, lat);
    else          spmm_body(bid - 32, row_start, csr, gate, out0);
}

// layer-1 latpart standalone (gate1 is produced by k_hyperlat(l0) epilogue)
__global__ __launch_bounds__(256) void k_latpart1(const u16* __restrict__ cur,
                                                  const u16* __restrict__ hyp,
                                                  float* __restrict__ part) {
    int bid = blockIdx.x;                  // grid = LPB
    latpart_body(bid >> 1, bid & 1, cur, hyp, part);
}

// hyperLat = leaky(hyp @ lat); outL = hyperLat; cur = bf16(hyperLat + tem);
// if emit: gate = bf16(cur) * (2*sigmoid(z)-1)  (next layer's gate, fused epilogue)
__global__ __launch_bounds__(256) void k_hyperlat(const u16* __restrict__ hyp,
                                                  const float* __restrict__ lat,
                                                  const float* __restrict__ tem0,
                                                  float* __restrict__ outL,
                                                  u16* __restrict__ cur,
                                                  const float* __restrict__ z,
                                                  u16* __restrict__ gate,
                                                  int emit) {
    __shared__ float lds[HHY * DD];   // 32 KB
    int t = threadIdx.x;
    for (int i = t; i < HHY * DD; i += 256) lds[i] = lat[i];
    __syncthreads();
    int w = t >> 6, d = t & 63;
    int r0 = blockIdx.x * 16 + w * 4;
    float acc[4] = {0.f, 0.f, 0.f, 0.f};
    for (int h0 = 0; h0 < HHY; h0 += 8) {
        u16 hr[4][8];
#pragma unroll
        for (int r = 0; r < 4; r++) {
            const ushort4* pp = (const ushort4*)(hyp + (size_t)(r0 + r) * HHY + h0);
            ushort4 a = pp[0], b = pp[1];
            hr[r][0] = a.x; hr[r][1] = a.y; hr[r][2] = a.z; hr[r][3] = a.w;
            hr[r][4] = b.x; hr[r][5] = b.y; hr[r][6] = b.z; hr[r][7] = b.w;
        }
#pragma unroll
        for (int j = 0; j < 8; j++) {
            float lv = lds[(h0 + j) * DD + d];
#pragma unroll
            for (int r = 0; r < 4; r++) acc[r] += us2f(hr[r][j]) * lv;
        }
    }
#pragma unroll
    for (int r = 0; r < 4; r++) {
        size_t off = (size_t)(r0 + r) * DD + d;
        float hl = lrelu(acc[r]);
        float tem = tem0[off];
        u16 cb = f2us(hl + tem);
        outL[off] = hl;                 // fp32 output
        cur[off] = cb;                  // bf16 intermediate for next layer
        if (emit) {
            float zz = z[off];
            // identical numerics to gate_body: input is the bf16-rounded cur
            gate[off] = f2us(us2f(cb) * (2.f / (1.f + __expf(-zz)) - 1.f));
        }
    }
}

// ---------------- launch ----------------

extern "C" void kernel_launch(void* const* d_in, const int* in_sizes, int n_in,
                              void* d_out, int out_size, void* d_ws, size_t ws_size,
                              hipStream_t stream) {
    const int*   rows  = (const int*)d_in[0];    // int32
    const int*   cols  = (const int*)d_in[1];    // int32
    const float* vals  = (const float*)d_in[2];  // fp32
    const float* uEmb  = (const float*)d_in[3];  // fp32
    const float* iEmb  = (const float*)d_in[4];  // fp32
    const float* Hyper = (const float*)d_in[5];  // fp32
    const float* zishi = (const float*)d_in[6];  // fp32
    // d_in[7] = keepRate (==1, static python branch) -> unused

    float* out = (float*)d_out;                  // fp32 output, [3, NN, DD]

    char* ws = (char*)d_ws;
    int2*  csr       = (int2*)(ws + 0);                 // 12,800,000
    int*   row_start = (int*)(ws + 12800000);           //    400,128 (padded)
    int*   counts    = (int*)(ws + 13600128);           //    400,000
    u16*   hyp       = (u16*)(ws + 14000128);           // 25,600,000
    u16*   cur       = (u16*)(ws + 39600128);           // 12,800,000
    float* lat       = (float*)(ws + 52400128);         //     32,768
    int*   bsum      = (int*)(ws + 52432896);           //      1,564 -> end 52,434,460

    // Scratch aliased onto d_out's slab2 (bytes 51.2MB..76.8MB of out, 25.6 MB):
    //   ranks (int,  6.4 MB) @ [0, 6.4M):    written k_hp_ah, last read k_pos.
    //   pos   (int,  6.4 MB) @ [6.4M,12.8M): written k_pos,  last read k_fused0.
    //   gate  (bf16, 12.8 MB) @ [0, 12.8M):  written k_gate(l0) / k_hyperlat(l0 epilogue),
    //                                        last read k_fused_sl of same layer.
    //   part  (fp32, 12.58 MB) @ [12.8M, 25.4M): written k_fused0/k_latpart1,
    //                                        last read k_fused_sl of same layer.
    // gate(l1) write in k_hyperlat(l0) is safe: ranks/pos/part(l0) all dead by then.
    // Final k_hyperlat(l=1) writes hyperLat2 over the whole slab last.
    char*  slab2 = (char*)(out + (size_t)2 * NN * DD);
    int*   ranks = (int*)slab2;
    int*   pos   = (int*)(slab2 + 6400000);
    u16*   gate  = (u16*)slab2;
    float* part  = (float*)(slab2 + 12800000);

    // CSR build + embeds prep + allhyper (fused)
    hipMemsetAsync(counts, 0, NN * sizeof(int), stream);
    k_hp_ah<<<2 * SCB, 256, 0, stream>>>(rows, counts, ranks,
                                         (const float4*)uEmb, (const float4*)iEmb,
                                         (ushort4*)cur, Hyper, hyp);
    k_blocksum<<<NSB, 256, 0, stream>>>(counts, bsum);
    k_scanb<<<1, 512, 0, stream>>>(bsum);
    k_scanfinal<<<NSB, 256, 0, stream>>>(counts, bsum, row_start);
    k_pos<<<SCB, 256, 0, stream>>>(rows, ranks, row_start, pos);

    float* out0 = out;  // tem slab (layer-2 spmm overwrites it, matching reference)

    // ---- layer 0 ----
    k_fused0<<<LPB + 8 * 3125, 256, 0, stream>>>(pos, cols, vals, csr, cur, hyp, part);
    k_gate<<<SCB, 256, 0, stream>>>((const ushort4*)cur, (const float4*)zishi, (ushort4*)gate);
    k_fused_sl<<<NN / 4 + 32, 256, 0, stream>>>(row_start, csr, gate, out0, part, lat);
    k_hyperlat<<<NN / 16, 256, 0, stream>>>(hyp, lat, out0, out + (size_t)1 * NN * DD, cur,
                                            zishi, gate, 1);   // emits gate for layer 1

    // ---- layer 1 ----
    k_latpart1<<<LPB, 256, 0, stream>>>(cur, hyp, part);
    k_fused_sl<<<NN / 4 + 32, 256, 0, stream>>>(row_start, csr, gate, out0, part, lat);
    k_hyperlat<<<NN / 16, 256, 0, stream>>>(hyp, lat, out0, out + (size_t)2 * NN * DD, cur,
                                            zishi, gate, 0);
}